// Round 9
// baseline (183.823 us; speedup 1.0000x reference)
//
#include <hip/hip_runtime.h>
#include <math.h>

// ---------------------------------------------------------------------------
// QuantumGenerator: ONE persistent kernel, 1024 blocks x 512 threads
// (__launch_bounds__(512,8) => 4 blocks/CU, 32 waves/CU = FULL occupancy;
// round-8 ran 16/32 waves and was latency-bound: VALU 29%, HBM 19%, occ 43%).
//
// KEY INVARIANT (re-verified for 512-thread mapping): block bid covers float
// window [2048*(bid&1), +2048) of batches {bid>>1, 512+(bid>>1)} at EVERY
// layer (CPB*HW = 2048 for all four) -> block bid's phase-N+1 reads come
// exactly from its own phase-N writes -> no cache maintenance needed.
// Cross-block data only: BN partials (atomicAdd at LLC, relaxed agent loads)
// + barrier state.
//
// Grid barrier v4: leaf(64x16)/mid(8x8)/root tree arrival, write-once DONE
// flags polled relaxed (no wbl2/buffer_inv anywhere); bounded spin.
//
// BN stats: per-thread ls/lss accumulated ACROSS iterations (bin is
// iteration-invariant) -> ONE shuffle tree + LDS atomic per phase (round-8
// did it per iteration: 4x the ds_permute/LDS-atomic traffic).
// Norm cancellation (exact): n^2=max(||x||^2,1e-18); d=(Vx)^2/max(S,1e-9*n^2)
// ---------------------------------------------------------------------------

#define NSLOT 32
#define NBLK  1024u
#define TPB   512

// ws float offsets
#define OFF_G2S 0        // 64*32
#define OFF_G2Q 2048     // 64*32
#define OFF_G3S 4096     // 16*32
#define OFF_G3Q 4608     // 16*32
#define OFF_G4S 5120     // 4*32
#define OFF_G4Q 5248     // 4*32
#define OFF_GFS 5376     // 1*32
#define OFF_GFQ 5408     // 1*32
#define OFF_CTR 5504     // 4 phases x 2192 uints
#define PHASE_STRIDE 2192
// memset covers [0 .. 5504 + 4*2192 = 14272) floats

__device__ __forceinline__ void gbar(unsigned* ctr, int phase)
{
    __syncthreads();   // vmcnt(0)+barrier: this block's stats atomics performed
    if (threadIdx.x == 0){
        unsigned* base  = ctr + phase*PHASE_STRIDE;
        const int  lf   = blockIdx.x & 63;
        unsigned* leaf  = base + (lf << 4);              // 64 lines, 16 arrivals ea
        unsigned* mid   = base + 1024 + ((lf >> 3) << 4);// 8 lines, 8 arrivals ea
        unsigned* root  = base + 1152;                   // 1 line, 8 arrivals
        unsigned* flags = base + 1168;                   // 64 write-once lines

        unsigned ol = __hip_atomic_fetch_add(leaf, 1u, __ATOMIC_RELAXED,
                                             __HIP_MEMORY_SCOPE_AGENT);
        if (ol == 15u){
            unsigned om = __hip_atomic_fetch_add(mid, 1u, __ATOMIC_RELAXED,
                                                 __HIP_MEMORY_SCOPE_AGENT);
            if (om == 7u){
                unsigned orr = __hip_atomic_fetch_add(root, 1u, __ATOMIC_RELAXED,
                                                      __HIP_MEMORY_SCOPE_AGENT);
                if (orr == 7u){
                    #pragma unroll
                    for (int i=0;i<64;i++)
                        __hip_atomic_store(flags + (i<<4), 1u, __ATOMIC_RELAXED,
                                           __HIP_MEMORY_SCOPE_AGENT);
                }
            }
        }
        unsigned* myflag = flags + (lf << 4);
        int spins = 0;
        while (__hip_atomic_load(myflag, __ATOMIC_RELAXED,
                                 __HIP_MEMORY_SCOPE_AGENT) == 0u){
            __builtin_amdgcn_s_sleep(2);
            if (++spins > 200000) break;    // failsafe: terminate, not hang
        }
        __atomic_signal_fence(__ATOMIC_SEQ_CST);  // compiler fence only
    }
    __syncthreads();
}

// read a BN partial slot from the coherent LLC (bypasses stale L1/L2)
__device__ __forceinline__ float llc_load(const float* p)
{
    return __hip_atomic_load(const_cast<float*>(p), __ATOMIC_RELAXED,
                             __HIP_MEMORY_SCOPE_AGENT);
}

template<int C, int H, int W, bool BN>
__device__ __forceinline__ void qcnn_phase(
    const float* __restrict__ x, const float* __restrict__ wl,
    const float* __restrict__ isum, const float* __restrict__ issq,
    const float* __restrict__ gamma, const float* __restrict__ beta,
    float invNin,
    float* __restrict__ out, float* __restrict__ osum, float* __restrict__ ossq,
    float* sBin, float* sV, float* sRed)
{
    constexpr int HW  = H*W;
    constexpr int P   = HW/4;                 // patches/channel: 4,16,64,256
    constexpr int OW  = W/2;
    constexpr int LP  = (P==4)?2:(P==16)?4:(P==64)?6:8;
    constexpr int LOW = (OW==2)?1:(OW==4)?2:(OW==8)?3:4;
    constexpr int CPB = TPB/P;                // input channels per block: 128,32,8,2
    constexpr int OCB = (TPB/(4*P)) < 1 ? 1 : (TPB/(4*P)); // BN bins: 32,8,2,1
    constexpr int G   = (4*P < 64) ? 4*P : 64;      // lanes sharing one BN bin

    const int c0 = (blockIdx.x & 1) * CPB;

    // ---- build this block's V channels (cols 0-3 only) into LDS ----
    if (threadIdx.x < CPB*4){
        const int cl = threadIdx.x >> 2;      // local channel
        const int k  = threadIdx.x & 3;       // column 0..3
        const float* w = wl + (c0+cl)*18;
        float v[8];
        #pragma unroll
        for (int r=0;r<8;r++) v[r] = (r==k) ? 1.0f : 0.0f;
        for (int l=0;l<6;l++){
            float ca = cosf(0.5f*w[l*3+0]), sa = sinf(0.5f*w[l*3+0]);
            float cb = cosf(0.5f*w[l*3+1]), sb = sinf(0.5f*w[l*3+1]);
            float cc = cosf(0.5f*w[l*3+2]), sc_ = sinf(0.5f*w[l*3+2]);
            #pragma unroll
            for (int b=0;b<8;b+=2){ float xx=v[b], yy=v[b+1]; v[b]=cc*xx-sc_*yy; v[b+1]=sc_*xx+cc*yy; }
            #pragma unroll
            for (int g=0; g<8; g+=4)
                #pragma unroll
                for (int i=0;i<2;i++){ int a=g+i, b=g+i+2; float xx=v[a], yy=v[b]; v[a]=cb*xx-sb*yy; v[b]=sb*xx+cb*yy; }
            #pragma unroll
            for (int i=0;i<4;i++){ float xx=v[i], yy=v[i+4]; v[i]=ca*xx-sa*yy; v[i+4]=sa*xx+ca*yy; }
            // CNOT ring: new[perm[r]] = old[r]; perm = {0,5,7,2,3,6,4,1}
            float nv[8];
            nv[0]=v[0]; nv[5]=v[1]; nv[7]=v[2]; nv[2]=v[3];
            nv[3]=v[4]; nv[6]=v[5]; nv[4]=v[6]; nv[1]=v[7];
            #pragma unroll
            for (int r=0;r<8;r++) v[r]=nv[r];
        }
        #pragma unroll
        for (int r=0;r<4;r++) sV[cl*16 + r*4 + k] = v[r];   // U[r][k]
    }
    if (threadIdx.x < 2*OCB) sBin[threadIdx.x] = 0.0f;
    if constexpr (BN){ if (threadIdx.x < 2*CPB) sRed[threadIdx.x] = 0.0f; }
    __syncthreads();

    if constexpr (BN){
        // cooperative load of 2*CPB*32 partial slots from LLC -> LDS reduce
        constexpr int TOT = 2*CPB*NSLOT;     // 2048 / 512 / 128
        for (int i=threadIdx.x; i<TOT; i+=TPB){
            const int arr  = i / (CPB*NSLOT);
            const int rem  = i - arr*(CPB*NSLOT);
            const int cl   = rem >> 5;
            const int slot = rem & 31;
            float v = llc_load((arr ? issq : isum) + (c0+cl)*NSLOT + slot);
            atomicAdd(&sRed[arr*CPB + cl], v);
        }
        __syncthreads();
    }

    const int r   = ((blockIdx.x & 1) << 9) + threadIdx.x;  // per-batch flat idx
    const int c   = r >> LP;
    const int p   = r & (P-1);
    const int oh  = p >> LOW;
    const int ow  = p & (OW-1);
    const int oc0 = ((blockIdx.x & 1) << 9) >> (LP+2);
    const int ocl = (r >> (LP+2)) - oc0;
    const int xoff = c*HW + (oh*2)*W + (ow*2);
    const int ooff = c*HW + (p<<2);

    float sc = 0.0f, sh = 0.0f;
    if constexpr (BN){
        const int cl = c - c0;
        float s = sRed[cl], q = sRed[CPB+cl];
        float mean = s * invNin;
        float var  = q * invNin - mean*mean;
        float rinv = 1.0f / sqrtf(var + 1e-5f);
        sc = gamma[c] * rinv;
        sh = beta[c] - mean * sc;
    }
    const float4* Vc = reinterpret_cast<const float4*>(sV + (c-c0)*16);
    const float4 v0 = Vc[0], v1 = Vc[1], v2 = Vc[2], v3 = Vc[3];

    float lsA = 0.0f, lssA = 0.0f;    // BN-stat accumulators (bin is iter-invariant)
    #pragma unroll
    for (int it=0; it<2; ++it){
        const int b = (it<<9) + (blockIdx.x>>1);
        const float* xb = x + ((size_t)b<<12) + xoff;
        float2 t0 = *reinterpret_cast<const float2*>(xb);
        float2 t1 = *reinterpret_cast<const float2*>(xb + W);
        float x0=t0.x, x1=t0.y, x2=t1.x, x3=t1.y;
        if constexpr (BN){
            x0 = fmaxf(x0*sc+sh, 0.0f);
            x1 = fmaxf(x1*sc+sh, 0.0f);
            x2 = fmaxf(x2*sc+sh, 0.0f);
            x3 = fmaxf(x3*sc+sh, 0.0f);
        }
        float nsq = x0*x0 + x1*x1 + x2*x2 + x3*x3;
        float q0 = v0.x*x0 + v0.y*x1 + v0.z*x2 + v0.w*x3;
        float q1 = v1.x*x0 + v1.y*x1 + v1.z*x2 + v1.w*x3;
        float q2 = v2.x*x0 + v2.y*x1 + v2.z*x2 + v2.w*x3;
        float q3 = v3.x*x0 + v3.y*x1 + v3.z*x2 + v3.w*x3;
        q0*=q0; q1*=q1; q2*=q2; q3*=q3;
        float s = q0+q1+q2+q3;
        float dinv = 1.0f / fmaxf(s, 1e-9f * fmaxf(nsq, 1e-18f));
        float d0=q0*dinv, d1=q1*dinv, d2=q2*dinv, d3=q3*dinv;
        *reinterpret_cast<float4*>(out + ((size_t)b<<12) + ooff) =
            make_float4(d0,d1,d2,d3);
        lsA  += d0+d1+d2+d3;
        lssA += d0*d0 + d1*d1 + d2*d2 + d3*d3;
    }
    // one shuffle tree + LDS atomic per phase (not per iteration)
    #pragma unroll
    for (int off=1; off<G; off<<=1){ lsA += __shfl_xor(lsA, off); lssA += __shfl_xor(lssA, off); }
    if ((threadIdx.x & (G-1)) == 0){
        atomicAdd(&sBin[ocl], lsA);
        atomicAdd(&sBin[OCB + ocl], lssA);
    }
    __syncthreads();
    if (threadIdx.x < OCB){
        const int slot = (blockIdx.x >> 1) & (NSLOT-1);   // ~16 adds per address
        atomicAdd(&osum[(oc0+threadIdx.x)*NSLOT + slot], sBin[threadIdx.x]);
        atomicAdd(&ossq[(oc0+threadIdx.x)*NSLOT + slot], sBin[OCB+threadIdx.x]);
    }
}

__global__ __launch_bounds__(TPB, 8) void fused_all(
    const float* __restrict__ z,
    const float* __restrict__ w1, const float* __restrict__ w2,
    const float* __restrict__ w3, const float* __restrict__ w4,
    const float* __restrict__ gamma2, const float* __restrict__ beta2,
    const float* __restrict__ gamma3, const float* __restrict__ beta3,
    const float* __restrict__ gamma4, const float* __restrict__ beta4,
    const float* __restrict__ gammaf, const float* __restrict__ betaf,
    float* __restrict__ out, float* __restrict__ ws)
{
    __shared__ float sBin[64];
    __shared__ float sV[2048];                // up to 128 ch x 16 floats
    __shared__ float sRed[64];
    unsigned* ctr = reinterpret_cast<unsigned*>(ws + OFF_CTR);
    float* bufA = ws + 65536;                 // 4M floats (s1, then s3)
    float* bufB = bufA + 4194304;             // 4M floats (s2)
    float* s4   = out + 4194304;              // output slot 1
    float* s4bn = out + 8388608;              // output slot 2
    const int gtid = blockIdx.x*TPB + threadIdx.x;

    // P1: L1  z(1024,256,4,4) -> s1(bufA); stats -> g2 (64 ch, N=65536)
    qcnn_phase<256,4,4,false>(z, w1, nullptr, nullptr, nullptr, nullptr, 0.0f,
                              bufA, ws+OFF_G2S, ws+OFF_G2Q, sBin, sV, sRed);
    gbar(ctr, 0);

    // P2: L2  relu(bn(s1)) -> s2(bufB); stats -> g3 (16 ch, N=262144)
    qcnn_phase<64,8,8,true>(bufA, w2, ws+OFF_G2S, ws+OFF_G2Q, gamma2, beta2,
                            1.0f/65536.0f, bufB, ws+OFF_G3S, ws+OFF_G3Q, sBin, sV, sRed);
    gbar(ctr, 1);

    // P3: L3 -> s3(bufA); stats -> g4 (4 ch, N=1048576)
    qcnn_phase<16,16,16,true>(bufB, w3, ws+OFF_G3S, ws+OFF_G3Q, gamma3, beta3,
                              1.0f/262144.0f, bufA, ws+OFF_G4S, ws+OFF_G4Q, sBin, sV, sRed);
    gbar(ctr, 2);

    // P4: L4 -> s4 (out slot 1); stats -> gf (1 ch, N=4194304)
    qcnn_phase<4,32,32,true>(bufA, w4, ws+OFF_G4S, ws+OFF_G4Q, gamma4, beta4,
                             1.0f/1048576.0f, s4, ws+OFF_GFS, ws+OFF_GFQ, sBin, sV, sRed);
    gbar(ctr, 3);

    // P5: final  s4_bn -> out slot 2, tanh -> out slot 0  (reads OWN s4 region)
    {
        // cooperative stat read: 64 lanes of wave 0 load the slots, shuffle-reduce
        float v = 0.0f;
        if (threadIdx.x < 64)
            v = llc_load(ws + (threadIdx.x < 32 ? OFF_GFS + threadIdx.x
                                                : OFF_GFQ + threadIdx.x - 32));
        #pragma unroll
        for (int off=1; off<32; off<<=1) v += __shfl_xor(v, off);
        if (threadIdx.x == 0)  sRed[0] = v;   // sum
        if (threadIdx.x == 32) sRed[1] = v;   // sum of squares
        __syncthreads();
        float s = sRed[0], q = sRed[1];
        float mean = s * (1.0f/4194304.0f);
        float var  = q * (1.0f/4194304.0f) - mean*mean;
        float rinv = 1.0f / sqrtf(var + 1e-5f);
        float sc = gammaf[0]*rinv;
        float sh = betaf[0] - mean*sc;
        #pragma unroll
        for (int k=0; k<2; ++k){
            int i = gtid + k*524288;                     // 1M float4s total
            float4 vv = reinterpret_cast<const float4*>(s4)[i];
            float4 bn = make_float4(vv.x*sc+sh, vv.y*sc+sh, vv.z*sc+sh, vv.w*sc+sh);
            reinterpret_cast<float4*>(s4bn)[i] = bn;
            reinterpret_cast<float4*>(out)[i] =
                make_float4(tanhf(bn.x), tanhf(bn.y), tanhf(bn.z), tanhf(bn.w));
        }
    }
}

extern "C" void kernel_launch(void* const* d_in, const int* in_sizes, int n_in,
                              void* d_out, int out_size, void* d_ws, size_t ws_size,
                              hipStream_t stream)
{
    const float* z      = (const float*)d_in[0];
    const float* w1     = (const float*)d_in[1];
    const float* w2     = (const float*)d_in[2];
    const float* w3     = (const float*)d_in[3];
    const float* w4     = (const float*)d_in[4];
    const float* gamma2 = (const float*)d_in[5];
    const float* beta2  = (const float*)d_in[6];
    const float* gamma3 = (const float*)d_in[7];
    const float* beta3  = (const float*)d_in[8];
    const float* gamma4 = (const float*)d_in[9];
    const float* beta4  = (const float*)d_in[10];
    const float* gammaf = (const float*)d_in[11];
    const float* betaf  = (const float*)d_in[12];
    float* out = (float*)d_out;
    float* ws  = (float*)d_ws;

    // zero BN partial slots + barrier counters/flags
    hipMemsetAsync(ws, 0, (5504 + 4*PHASE_STRIDE) * sizeof(float), stream);

    fused_all<<<NBLK, TPB, 0, stream>>>(
        z, w1, w2, w3, w4, gamma2, beta2, gamma3, beta3,
        gamma4, beta4, gammaf, betaf, out, ws);
}

// Round 10
// 174.016 us; speedup vs baseline: 1.0564x; 1.0564x over previous
//
#include <hip/hip_runtime.h>
#include <math.h>

// ---------------------------------------------------------------------------
// QuantumGenerator: ONE persistent kernel, 1024 blocks x 512 threads
// (__launch_bounds__(512,8) => 4 blocks/CU, 32 waves/CU).
//
// ROUND-10 CHANGE: V built ONCE globally (phase 0) instead of per-block.
// Round-9 post-mortem: each column-build = ~1100 VALU instr (36 sincos) and
// every block redundantly rebuilt its channels (131K builds for 340 needed)
// => ~27us of redundant trig/dispatch.  Now: 1360 column-builds lane-parallel
// in blocks 0..679 (~2us), written to a global V table via AGENT-scope
// relaxed atomic stores (performed at coherent LLC -- same mechanism as the
// BN partials, proven since round 3).  Consumers cooperatively llc_load
// their CPB*16 floats into LDS per phase (<=4 loads/thread).
//
// KEY INVARIANT: block bid covers float window [2048*(bid&1), +2048) of
// batches {bid>>1, 512+(bid>>1)} at EVERY layer -> phase-N+1 reads come
// exactly from own phase-N writes -> no cache maintenance.  Cross-block data
// only: BN partials + V table (LLC atomics), barrier state.
//
// Grid barrier v4: leaf(64x16)/mid(8x8)/root arrival tree, write-once DONE
// flags polled relaxed (no wbl2/buffer_inv); bounded spin. 5 barriers.
//
// BN stats hoisted: one shuffle tree + LDS atomic per phase.
// Norm cancellation (exact): n^2=max(||x||^2,1e-18); d=(Vx)^2/max(S,1e-9*n^2)
// ---------------------------------------------------------------------------

#define NSLOT 32
#define NBLK  1024u
#define TPB   512

// ws float offsets
#define OFF_G2S 0        // 64*32
#define OFF_G2Q 2048     // 64*32
#define OFF_G3S 4096     // 16*32
#define OFF_G3Q 4608     // 16*32
#define OFF_G4S 5120     // 4*32
#define OFF_G4Q 5248     // 4*32
#define OFF_GFS 5376     // 1*32
#define OFF_GFQ 5408     // 1*32
#define OFF_CTR 5504     // 5 phases x 2192 uints
#define PHASE_STRIDE 2192
#define OFF_VG  16512    // 340*16 global V table (all entries written in P0)
// memset covers [0 .. 5504 + 5*2192 = 16464) floats

__device__ __forceinline__ void gbar(unsigned* ctr, int phase)
{
    __syncthreads();   // vmcnt(0)+barrier: this block's LLC stores performed
    if (threadIdx.x == 0){
        unsigned* base  = ctr + phase*PHASE_STRIDE;
        const int  lf   = blockIdx.x & 63;
        unsigned* leaf  = base + (lf << 4);              // 64 lines, 16 arrivals ea
        unsigned* mid   = base + 1024 + ((lf >> 3) << 4);// 8 lines, 8 arrivals ea
        unsigned* root  = base + 1152;                   // 1 line, 8 arrivals
        unsigned* flags = base + 1168;                   // 64 write-once lines

        unsigned ol = __hip_atomic_fetch_add(leaf, 1u, __ATOMIC_RELAXED,
                                             __HIP_MEMORY_SCOPE_AGENT);
        if (ol == 15u){
            unsigned om = __hip_atomic_fetch_add(mid, 1u, __ATOMIC_RELAXED,
                                                 __HIP_MEMORY_SCOPE_AGENT);
            if (om == 7u){
                unsigned orr = __hip_atomic_fetch_add(root, 1u, __ATOMIC_RELAXED,
                                                      __HIP_MEMORY_SCOPE_AGENT);
                if (orr == 7u){
                    #pragma unroll
                    for (int i=0;i<64;i++)
                        __hip_atomic_store(flags + (i<<4), 1u, __ATOMIC_RELAXED,
                                           __HIP_MEMORY_SCOPE_AGENT);
                }
            }
        }
        unsigned* myflag = flags + (lf << 4);
        int spins = 0;
        while (__hip_atomic_load(myflag, __ATOMIC_RELAXED,
                                 __HIP_MEMORY_SCOPE_AGENT) == 0u){
            __builtin_amdgcn_s_sleep(2);
            if (++spins > 200000) break;    // failsafe: terminate, not hang
        }
        __atomic_signal_fence(__ATOMIC_SEQ_CST);  // compiler fence only
    }
    __syncthreads();
}

// coherent-LLC scalar access (bypasses non-coherent per-XCD L2)
__device__ __forceinline__ float llc_load(const float* p)
{
    return __hip_atomic_load(const_cast<float*>(p), __ATOMIC_RELAXED,
                             __HIP_MEMORY_SCOPE_AGENT);
}
__device__ __forceinline__ void llc_store(float* p, float v)
{
    __hip_atomic_store(p, v, __ATOMIC_RELAXED, __HIP_MEMORY_SCOPE_AGENT);
}

template<int C, int H, int W, bool BN>
__device__ __forceinline__ void qcnn_phase(
    const float* __restrict__ x, const float* __restrict__ Vg,
    const float* __restrict__ isum, const float* __restrict__ issq,
    const float* __restrict__ gamma, const float* __restrict__ beta,
    float invNin,
    float* __restrict__ out, float* __restrict__ osum, float* __restrict__ ossq,
    float* sBin, float* sV, float* sRed)
{
    constexpr int HW  = H*W;
    constexpr int P   = HW/4;                 // patches/channel: 4,16,64,256
    constexpr int OW  = W/2;
    constexpr int LP  = (P==4)?2:(P==16)?4:(P==64)?6:8;
    constexpr int LOW = (OW==2)?1:(OW==4)?2:(OW==8)?3:4;
    constexpr int CPB = TPB/P;                // input channels per block: 128,32,8,2
    constexpr int OCB = (TPB/(4*P)) < 1 ? 1 : (TPB/(4*P)); // BN bins: 32,8,2,1
    constexpr int G   = (4*P < 64) ? 4*P : 64;      // lanes sharing one BN bin

    const int c0 = (blockIdx.x & 1) * CPB;

    // ---- cooperative V fetch: CPB*16 floats from LLC -> LDS ----
    for (int i = threadIdx.x; i < CPB*16; i += TPB)
        sV[i] = llc_load(Vg + c0*16 + i);
    if (threadIdx.x < 2*OCB) sBin[threadIdx.x] = 0.0f;
    if constexpr (BN){ if (threadIdx.x < 2*CPB) sRed[threadIdx.x] = 0.0f; }
    __syncthreads();

    if constexpr (BN){
        // cooperative load of 2*CPB*32 partial slots from LLC -> LDS reduce
        constexpr int TOT = 2*CPB*NSLOT;     // 2048 / 512 / 128
        for (int i=threadIdx.x; i<TOT; i+=TPB){
            const int arr  = i / (CPB*NSLOT);
            const int rem  = i - arr*(CPB*NSLOT);
            const int cl   = rem >> 5;
            const int slot = rem & 31;
            float v = llc_load((arr ? issq : isum) + (c0+cl)*NSLOT + slot);
            atomicAdd(&sRed[arr*CPB + cl], v);
        }
        __syncthreads();
    }

    const int r   = ((blockIdx.x & 1) << 9) + threadIdx.x;  // per-batch flat idx
    const int c   = r >> LP;
    const int p   = r & (P-1);
    const int oh  = p >> LOW;
    const int ow  = p & (OW-1);
    const int oc0 = ((blockIdx.x & 1) << 9) >> (LP+2);
    const int ocl = (r >> (LP+2)) - oc0;
    const int xoff = c*HW + (oh*2)*W + (ow*2);
    const int ooff = c*HW + (p<<2);

    float sc = 0.0f, sh = 0.0f;
    if constexpr (BN){
        const int cl = c - c0;
        float s = sRed[cl], q = sRed[CPB+cl];
        float mean = s * invNin;
        float var  = q * invNin - mean*mean;
        float rinv = 1.0f / sqrtf(var + 1e-5f);
        sc = gamma[c] * rinv;
        sh = beta[c] - mean * sc;
    }
    const float4* Vc = reinterpret_cast<const float4*>(sV + (c-c0)*16);
    const float4 v0 = Vc[0], v1 = Vc[1], v2 = Vc[2], v3 = Vc[3];

    float lsA = 0.0f, lssA = 0.0f;    // BN-stat accumulators (bin iter-invariant)
    #pragma unroll
    for (int it=0; it<2; ++it){
        const int b = (it<<9) + (blockIdx.x>>1);
        const float* xb = x + ((size_t)b<<12) + xoff;
        float2 t0 = *reinterpret_cast<const float2*>(xb);
        float2 t1 = *reinterpret_cast<const float2*>(xb + W);
        float x0=t0.x, x1=t0.y, x2=t1.x, x3=t1.y;
        if constexpr (BN){
            x0 = fmaxf(x0*sc+sh, 0.0f);
            x1 = fmaxf(x1*sc+sh, 0.0f);
            x2 = fmaxf(x2*sc+sh, 0.0f);
            x3 = fmaxf(x3*sc+sh, 0.0f);
        }
        float nsq = x0*x0 + x1*x1 + x2*x2 + x3*x3;
        float q0 = v0.x*x0 + v0.y*x1 + v0.z*x2 + v0.w*x3;
        float q1 = v1.x*x0 + v1.y*x1 + v1.z*x2 + v1.w*x3;
        float q2 = v2.x*x0 + v2.y*x1 + v2.z*x2 + v2.w*x3;
        float q3 = v3.x*x0 + v3.y*x1 + v3.z*x2 + v3.w*x3;
        q0*=q0; q1*=q1; q2*=q2; q3*=q3;
        float s = q0+q1+q2+q3;
        float dinv = 1.0f / fmaxf(s, 1e-9f * fmaxf(nsq, 1e-18f));
        float d0=q0*dinv, d1=q1*dinv, d2=q2*dinv, d3=q3*dinv;
        *reinterpret_cast<float4*>(out + ((size_t)b<<12) + ooff) =
            make_float4(d0,d1,d2,d3);
        lsA  += d0+d1+d2+d3;
        lssA += d0*d0 + d1*d1 + d2*d2 + d3*d3;
    }
    // one shuffle tree + LDS atomic per phase
    #pragma unroll
    for (int off=1; off<G; off<<=1){ lsA += __shfl_xor(lsA, off); lssA += __shfl_xor(lssA, off); }
    if ((threadIdx.x & (G-1)) == 0){
        atomicAdd(&sBin[ocl], lsA);
        atomicAdd(&sBin[OCB + ocl], lssA);
    }
    __syncthreads();
    if (threadIdx.x < OCB){
        const int slot = (blockIdx.x >> 1) & (NSLOT-1);   // ~16 adds per address
        atomicAdd(&osum[(oc0+threadIdx.x)*NSLOT + slot], sBin[threadIdx.x]);
        atomicAdd(&ossq[(oc0+threadIdx.x)*NSLOT + slot], sBin[OCB+threadIdx.x]);
    }
}

__global__ __launch_bounds__(TPB, 8) void fused_all(
    const float* __restrict__ z,
    const float* __restrict__ w1, const float* __restrict__ w2,
    const float* __restrict__ w3, const float* __restrict__ w4,
    const float* __restrict__ gamma2, const float* __restrict__ beta2,
    const float* __restrict__ gamma3, const float* __restrict__ beta3,
    const float* __restrict__ gamma4, const float* __restrict__ beta4,
    const float* __restrict__ gammaf, const float* __restrict__ betaf,
    float* __restrict__ out, float* __restrict__ ws)
{
    __shared__ float sBin[64];
    __shared__ float sV[2048];                // up to 128 ch x 16 floats
    __shared__ float sRed[64];
    unsigned* ctr = reinterpret_cast<unsigned*>(ws + OFF_CTR);
    float* Vg   = ws + OFF_VG;                // 340 ch x 16 (L1:0 L2:256 L3:320 L4:336)
    float* bufA = ws + 65536;                 // 4M floats (s1, then s3)
    float* bufB = bufA + 4194304;             // 4M floats (s2)
    float* s4   = out + 4194304;              // output slot 1
    float* s4bn = out + 8388608;              // output slot 2
    const int gtid = blockIdx.x*TPB + threadIdx.x;

    // P0: global V build -- 1360 (channel,column) builds, lane-parallel across
    // blocks 0..679 (threads 0,1 of each). ~1100 VALU instr each, once total.
    {
        const int t = blockIdx.x*2 + threadIdx.x;     // threadIdx.x < 2
        if (threadIdx.x < 2 && t < 1360){
            const int ch = t >> 2, k = t & 3;
            const float* w;
            if (ch < 256)      w = w1 + ch*18;
            else if (ch < 320) w = w2 + (ch-256)*18;
            else if (ch < 336) w = w3 + (ch-320)*18;
            else               w = w4 + (ch-336)*18;
            float v[8];
            #pragma unroll
            for (int r=0;r<8;r++) v[r] = (r==k) ? 1.0f : 0.0f;
            for (int l=0;l<6;l++){
                float ca = cosf(0.5f*w[l*3+0]), sa = sinf(0.5f*w[l*3+0]);
                float cb = cosf(0.5f*w[l*3+1]), sb = sinf(0.5f*w[l*3+1]);
                float cc = cosf(0.5f*w[l*3+2]), sc_ = sinf(0.5f*w[l*3+2]);
                #pragma unroll
                for (int b=0;b<8;b+=2){ float xx=v[b], yy=v[b+1]; v[b]=cc*xx-sc_*yy; v[b+1]=sc_*xx+cc*yy; }
                #pragma unroll
                for (int g=0; g<8; g+=4)
                    #pragma unroll
                    for (int i=0;i<2;i++){ int a=g+i, b=g+i+2; float xx=v[a], yy=v[b]; v[a]=cb*xx-sb*yy; v[b]=sb*xx+cb*yy; }
                #pragma unroll
                for (int i=0;i<4;i++){ float xx=v[i], yy=v[i+4]; v[i]=ca*xx-sa*yy; v[i+4]=sa*xx+ca*yy; }
                // CNOT ring: new[perm[r]] = old[r]; perm = {0,5,7,2,3,6,4,1}
                float nv[8];
                nv[0]=v[0]; nv[5]=v[1]; nv[7]=v[2]; nv[2]=v[3];
                nv[3]=v[4]; nv[6]=v[5]; nv[4]=v[6]; nv[1]=v[7];
                #pragma unroll
                for (int r=0;r<8;r++) v[r]=nv[r];
            }
            #pragma unroll
            for (int r=0;r<4;r++) llc_store(Vg + ch*16 + r*4 + k, v[r]);  // U[r][k]
        }
    }
    gbar(ctr, 0);

    // P1: L1  z(1024,256,4,4) -> s1(bufA); stats -> g2 (64 ch, N=65536)
    qcnn_phase<256,4,4,false>(z, Vg, nullptr, nullptr, nullptr, nullptr, 0.0f,
                              bufA, ws+OFF_G2S, ws+OFF_G2Q, sBin, sV, sRed);
    gbar(ctr, 1);

    // P2: L2  relu(bn(s1)) -> s2(bufB); stats -> g3 (16 ch, N=262144)
    qcnn_phase<64,8,8,true>(bufA, Vg+256*16, ws+OFF_G2S, ws+OFF_G2Q, gamma2, beta2,
                            1.0f/65536.0f, bufB, ws+OFF_G3S, ws+OFF_G3Q, sBin, sV, sRed);
    gbar(ctr, 2);

    // P3: L3 -> s3(bufA); stats -> g4 (4 ch, N=1048576)
    qcnn_phase<16,16,16,true>(bufB, Vg+320*16, ws+OFF_G3S, ws+OFF_G3Q, gamma3, beta3,
                              1.0f/262144.0f, bufA, ws+OFF_G4S, ws+OFF_G4Q, sBin, sV, sRed);
    gbar(ctr, 3);

    // P4: L4 -> s4 (out slot 1); stats -> gf (1 ch, N=4194304)
    qcnn_phase<4,32,32,true>(bufA, Vg+336*16, ws+OFF_G4S, ws+OFF_G4Q, gamma4, beta4,
                             1.0f/1048576.0f, s4, ws+OFF_GFS, ws+OFF_GFQ, sBin, sV, sRed);
    gbar(ctr, 4);

    // P5: final  s4_bn -> out slot 2, tanh -> out slot 0  (reads OWN s4 region)
    {
        float v = 0.0f;
        if (threadIdx.x < 64)
            v = llc_load(ws + (threadIdx.x < 32 ? OFF_GFS + threadIdx.x
                                                : OFF_GFQ + threadIdx.x - 32));
        #pragma unroll
        for (int off=1; off<32; off<<=1) v += __shfl_xor(v, off);
        if (threadIdx.x == 0)  sRed[0] = v;   // sum
        if (threadIdx.x == 32) sRed[1] = v;   // sum of squares
        __syncthreads();
        float s = sRed[0], q = sRed[1];
        float mean = s * (1.0f/4194304.0f);
        float var  = q * (1.0f/4194304.0f) - mean*mean;
        float rinv = 1.0f / sqrtf(var + 1e-5f);
        float sc = gammaf[0]*rinv;
        float sh = betaf[0] - mean*sc;
        #pragma unroll
        for (int k=0; k<2; ++k){
            int i = gtid + k*524288;                     // 1M float4s total
            float4 vv = reinterpret_cast<const float4*>(s4)[i];
            float4 bn = make_float4(vv.x*sc+sh, vv.y*sc+sh, vv.z*sc+sh, vv.w*sc+sh);
            reinterpret_cast<float4*>(s4bn)[i] = bn;
            reinterpret_cast<float4*>(out)[i] =
                make_float4(tanhf(bn.x), tanhf(bn.y), tanhf(bn.z), tanhf(bn.w));
        }
    }
}

extern "C" void kernel_launch(void* const* d_in, const int* in_sizes, int n_in,
                              void* d_out, int out_size, void* d_ws, size_t ws_size,
                              hipStream_t stream)
{
    const float* z      = (const float*)d_in[0];
    const float* w1     = (const float*)d_in[1];
    const float* w2     = (const float*)d_in[2];
    const float* w3     = (const float*)d_in[3];
    const float* w4     = (const float*)d_in[4];
    const float* gamma2 = (const float*)d_in[5];
    const float* beta2  = (const float*)d_in[6];
    const float* gamma3 = (const float*)d_in[7];
    const float* beta3  = (const float*)d_in[8];
    const float* gamma4 = (const float*)d_in[9];
    const float* beta4  = (const float*)d_in[10];
    const float* gammaf = (const float*)d_in[11];
    const float* betaf  = (const float*)d_in[12];
    float* out = (float*)d_out;
    float* ws  = (float*)d_ws;

    // zero BN partial slots + barrier counters/flags (V table fully overwritten)
    hipMemsetAsync(ws, 0, (5504 + 5*PHASE_STRIDE) * sizeof(float), stream);

    fused_all<<<NBLK, TPB, 0, stream>>>(
        z, w1, w2, w3, w4, gamma2, beta2, gamma3, beta3,
        gamma4, beta4, gammaf, betaf, out, ws);
}

// Round 11
// 170.946 us; speedup vs baseline: 1.0753x; 1.0180x over previous
//
#include <hip/hip_runtime.h>
#include <math.h>

// ---------------------------------------------------------------------------
// QuantumGenerator: ONE persistent kernel, 1024 blocks x 512 threads
// (__launch_bounds__(512,8) => 4 blocks/CU, 32 waves/CU).
//
// ROUND-11 CHANGE: inter-phase tensors live entirely in LDS.
// Per block the phase-to-phase data window is only 16KB (2 batches x 2048
// floats), and the producer's LDS-local write offset is universally 4*tid
// (c*HW + 4p = 4r at every layer).  So s1/s2/s3 NEVER touch global memory:
// each phase reads sX into registers, syncthreads, computes, writes sX.
// Only P4 stores s4 (a required output); P5 reads its own thread's sX slot.
// HBM traffic 139 -> ~70 MB; inter-phase load chains become ~120cy LDS reads.
// LDS 25KB/block x 4 = 100KB < 160KB -> co-residency preserved.
//
// V built ONCE globally (phase 0, 1360 lane-parallel column-builds, ~2us),
// via agent-scope relaxed atomic stores at the coherent LLC; consumers
// cooperatively llc_load CPB*16 floats into LDS per phase.
//
// Cross-block data ONLY: BN partials + V table (LLC atomics) + barrier state.
// Grid barrier v4: leaf(64x16)/mid(8x8)/root arrival tree, write-once DONE
// flags polled relaxed (no wbl2/buffer_inv); bounded spin.  5 barriers.
// BN stats hoisted: one shuffle tree + LDS atomic per phase.
// Norm cancellation (exact): n^2=max(||x||^2,1e-18); d=(Vx)^2/max(S,1e-9*n^2)
// ---------------------------------------------------------------------------

#define NSLOT 32
#define NBLK  1024u
#define TPB   512

// ws float offsets
#define OFF_G2S 0        // 64*32
#define OFF_G2Q 2048     // 64*32
#define OFF_G3S 4096     // 16*32
#define OFF_G3Q 4608     // 16*32
#define OFF_G4S 5120     // 4*32
#define OFF_G4Q 5248     // 4*32
#define OFF_GFS 5376     // 1*32
#define OFF_GFQ 5408     // 1*32
#define OFF_CTR 5504     // 5 phases x 2192 uints
#define PHASE_STRIDE 2192
#define OFF_VG  16512    // 340*16 global V table (fully written in P0)
// memset covers [0 .. 5504 + 5*2192 = 16464) floats

__device__ __forceinline__ void gbar(unsigned* ctr, int phase)
{
    __syncthreads();   // vmcnt(0)+barrier: this block's LLC stores performed
    if (threadIdx.x == 0){
        unsigned* base  = ctr + phase*PHASE_STRIDE;
        const int  lf   = blockIdx.x & 63;
        unsigned* leaf  = base + (lf << 4);              // 64 lines, 16 arrivals ea
        unsigned* mid   = base + 1024 + ((lf >> 3) << 4);// 8 lines, 8 arrivals ea
        unsigned* root  = base + 1152;                   // 1 line, 8 arrivals
        unsigned* flags = base + 1168;                   // 64 write-once lines

        unsigned ol = __hip_atomic_fetch_add(leaf, 1u, __ATOMIC_RELAXED,
                                             __HIP_MEMORY_SCOPE_AGENT);
        if (ol == 15u){
            unsigned om = __hip_atomic_fetch_add(mid, 1u, __ATOMIC_RELAXED,
                                                 __HIP_MEMORY_SCOPE_AGENT);
            if (om == 7u){
                unsigned orr = __hip_atomic_fetch_add(root, 1u, __ATOMIC_RELAXED,
                                                      __HIP_MEMORY_SCOPE_AGENT);
                if (orr == 7u){
                    #pragma unroll
                    for (int i=0;i<64;i++)
                        __hip_atomic_store(flags + (i<<4), 1u, __ATOMIC_RELAXED,
                                           __HIP_MEMORY_SCOPE_AGENT);
                }
            }
        }
        unsigned* myflag = flags + (lf << 4);
        int spins = 0;
        while (__hip_atomic_load(myflag, __ATOMIC_RELAXED,
                                 __HIP_MEMORY_SCOPE_AGENT) == 0u){
            __builtin_amdgcn_s_sleep(2);
            if (++spins > 200000) break;    // failsafe: terminate, not hang
        }
        __atomic_signal_fence(__ATOMIC_SEQ_CST);  // compiler fence only
    }
    __syncthreads();
}

// coherent-LLC scalar access (bypasses non-coherent per-XCD L2)
__device__ __forceinline__ float llc_load(const float* p)
{
    return __hip_atomic_load(const_cast<float*>(p), __ATOMIC_RELAXED,
                             __HIP_MEMORY_SCOPE_AGENT);
}
__device__ __forceinline__ void llc_store(float* p, float v)
{
    __hip_atomic_store(p, v, __ATOMIC_RELAXED, __HIP_MEMORY_SCOPE_AGENT);
}

// FIRST: read input from global xg; else from sX (LDS).  WG: also store
// the result to global outg (only the last qcnn layer needs it).
template<int C, int H, int W, bool BN, bool FIRST, bool WG>
__device__ __forceinline__ void qcnn_phase(
    const float* __restrict__ xg, const float* __restrict__ Vg,
    const float* __restrict__ isum, const float* __restrict__ issq,
    const float* __restrict__ gamma, const float* __restrict__ beta,
    float invNin, float* __restrict__ outg,
    float* __restrict__ osum, float* __restrict__ ossq,
    float* sBin, float* sV, float* sRed, float* sX)
{
    constexpr int HW  = H*W;
    constexpr int P   = HW/4;                 // patches/channel: 4,16,64,256
    constexpr int OW  = W/2;
    constexpr int LP  = (P==4)?2:(P==16)?4:(P==64)?6:8;
    constexpr int LOW = (OW==2)?1:(OW==4)?2:(OW==8)?3:4;
    constexpr int CPB = TPB/P;                // input channels/block: 128,32,8,2
    constexpr int OCB = (TPB/(4*P)) < 1 ? 1 : (TPB/(4*P)); // BN bins: 32,8,2,1
    constexpr int G   = (4*P < 64) ? 4*P : 64;      // lanes sharing one BN bin

    const int w  = blockIdx.x & 1;
    const int c0 = w * CPB;

    // cooperative V fetch: CPB*16 floats from LLC -> LDS
    for (int i = threadIdx.x; i < CPB*16; i += TPB)
        sV[i] = llc_load(Vg + c0*16 + i);
    if (threadIdx.x < 2*OCB) sBin[threadIdx.x] = 0.0f;
    if constexpr (BN){ if (threadIdx.x < 2*CPB) sRed[threadIdx.x] = 0.0f; }
    __syncthreads();

    if constexpr (BN){
        constexpr int TOT = 2*CPB*NSLOT;     // cooperative stats load -> LDS
        for (int i=threadIdx.x; i<TOT; i+=TPB){
            const int arr  = i / (CPB*NSLOT);
            const int rem  = i - arr*(CPB*NSLOT);
            const int cl   = rem >> 5;
            const int slot = rem & 31;
            float v = llc_load((arr ? issq : isum) + (c0+cl)*NSLOT + slot);
            atomicAdd(&sRed[arr*CPB + cl], v);
        }
        __syncthreads();
    }

    const int r   = (w << 9) + threadIdx.x;   // per-batch flat idx
    const int c   = r >> LP;
    const int p   = r & (P-1);
    const int oh  = p >> LOW;
    const int ow  = p & (OW-1);
    const int oc0 = (w << 9) >> (LP+2);
    const int ocl = (r >> (LP+2)) - oc0;
    const int cl  = c - c0;
    const int xl  = cl*HW + (oh*2)*W + ow*2;  // LDS-local input offset

    float sc = 0.0f, sh = 0.0f;
    if constexpr (BN){
        float s = sRed[cl], q = sRed[CPB+cl];
        float mean = s * invNin;
        float var  = q * invNin - mean*mean;
        float rinv = 1.0f / sqrtf(var + 1e-5f);
        sc = gamma[c] * rinv;
        sh = beta[c] - mean * sc;
    }
    const float4* Vc = reinterpret_cast<const float4*>(sV + cl*16);
    const float4 v0 = Vc[0], v1 = Vc[1], v2 = Vc[2], v3 = Vc[3];

    // load both batches' inputs into registers BEFORE overwriting sX
    float xi[2][4];
    #pragma unroll
    for (int it=0; it<2; ++it){
        if constexpr (FIRST){
            const int b = (it<<9) + (int)(blockIdx.x>>1);
            const float* xb = xg + ((size_t)b<<12) + c*HW + (oh*2)*W + ow*2;
            float2 t0 = *reinterpret_cast<const float2*>(xb);
            float2 t1 = *reinterpret_cast<const float2*>(xb + W);
            xi[it][0]=t0.x; xi[it][1]=t0.y; xi[it][2]=t1.x; xi[it][3]=t1.y;
        } else {
            float2 t0 = *reinterpret_cast<const float2*>(&sX[it*2048 + xl]);
            float2 t1 = *reinterpret_cast<const float2*>(&sX[it*2048 + xl + W]);
            xi[it][0]=t0.x; xi[it][1]=t0.y; xi[it][2]=t1.x; xi[it][3]=t1.y;
        }
    }
    if constexpr (!FIRST) __syncthreads();   // all reads done before overwrite

    float lsA = 0.0f, lssA = 0.0f;
    #pragma unroll
    for (int it=0; it<2; ++it){
        float x0=xi[it][0], x1=xi[it][1], x2=xi[it][2], x3=xi[it][3];
        if constexpr (BN){
            x0 = fmaxf(x0*sc+sh, 0.0f);
            x1 = fmaxf(x1*sc+sh, 0.0f);
            x2 = fmaxf(x2*sc+sh, 0.0f);
            x3 = fmaxf(x3*sc+sh, 0.0f);
        }
        float nsq = x0*x0 + x1*x1 + x2*x2 + x3*x3;
        float q0 = v0.x*x0 + v0.y*x1 + v0.z*x2 + v0.w*x3;
        float q1 = v1.x*x0 + v1.y*x1 + v1.z*x2 + v1.w*x3;
        float q2 = v2.x*x0 + v2.y*x1 + v2.z*x2 + v2.w*x3;
        float q3 = v3.x*x0 + v3.y*x1 + v3.z*x2 + v3.w*x3;
        q0*=q0; q1*=q1; q2*=q2; q3*=q3;
        float s = q0+q1+q2+q3;
        float dinv = 1.0f / fmaxf(s, 1e-9f * fmaxf(nsq, 1e-18f));
        float d0=q0*dinv, d1=q1*dinv, d2=q2*dinv, d3=q3*dinv;
        *reinterpret_cast<float4*>(&sX[it*2048 + 4*threadIdx.x]) =
            make_float4(d0,d1,d2,d3);          // local write offset = 4*tid
        if constexpr (WG){
            const int b = (it<<9) + (int)(blockIdx.x>>1);
            *reinterpret_cast<float4*>(outg + ((size_t)b<<12) + (w<<11)
                                       + 4*threadIdx.x) = make_float4(d0,d1,d2,d3);
        }
        lsA  += d0+d1+d2+d3;
        lssA += d0*d0 + d1*d1 + d2*d2 + d3*d3;
    }
    // one shuffle tree + LDS atomic per phase
    #pragma unroll
    for (int off=1; off<G; off<<=1){ lsA += __shfl_xor(lsA, off); lssA += __shfl_xor(lssA, off); }
    if ((threadIdx.x & (G-1)) == 0){
        atomicAdd(&sBin[ocl], lsA);
        atomicAdd(&sBin[OCB + ocl], lssA);
    }
    __syncthreads();
    if (threadIdx.x < OCB){
        const int slot = (blockIdx.x >> 1) & (NSLOT-1);   // ~16 adds per address
        atomicAdd(&osum[(oc0+threadIdx.x)*NSLOT + slot], sBin[threadIdx.x]);
        atomicAdd(&ossq[(oc0+threadIdx.x)*NSLOT + slot], sBin[OCB+threadIdx.x]);
    }
}

__global__ __launch_bounds__(TPB, 8) void fused_all(
    const float* __restrict__ z,
    const float* __restrict__ w1, const float* __restrict__ w2,
    const float* __restrict__ w3, const float* __restrict__ w4,
    const float* __restrict__ gamma2, const float* __restrict__ beta2,
    const float* __restrict__ gamma3, const float* __restrict__ beta3,
    const float* __restrict__ gamma4, const float* __restrict__ beta4,
    const float* __restrict__ gammaf, const float* __restrict__ betaf,
    float* __restrict__ out, float* __restrict__ ws)
{
    __shared__ float sBin[64];
    __shared__ float sV[2048];                // up to 128 ch x 16 floats (8KB)
    __shared__ float sRed[64];
    __shared__ float sX[4096];                // 2 batches x 2048 floats (16KB)
    unsigned* ctr = reinterpret_cast<unsigned*>(ws + OFF_CTR);
    float* Vg   = ws + OFF_VG;                // 340 ch x 16
    float* s4   = out + 4194304;              // output slot 1
    float* s4bn = out + 8388608;              // output slot 2
    const int w = blockIdx.x & 1;

    // P0: global V build -- 1360 (channel,column) builds, lane-parallel across
    // blocks 0..679 (threads 0,1 of each).
    {
        const int t = blockIdx.x*2 + threadIdx.x;     // threadIdx.x < 2
        if (threadIdx.x < 2 && t < 1360){
            const int ch = t >> 2, k = t & 3;
            const float* wp;
            if (ch < 256)      wp = w1 + ch*18;
            else if (ch < 320) wp = w2 + (ch-256)*18;
            else if (ch < 336) wp = w3 + (ch-320)*18;
            else               wp = w4 + (ch-336)*18;
            float v[8];
            #pragma unroll
            for (int r=0;r<8;r++) v[r] = (r==k) ? 1.0f : 0.0f;
            for (int l=0;l<6;l++){
                float ca = cosf(0.5f*wp[l*3+0]), sa = sinf(0.5f*wp[l*3+0]);
                float cb = cosf(0.5f*wp[l*3+1]), sb = sinf(0.5f*wp[l*3+1]);
                float cc = cosf(0.5f*wp[l*3+2]), sc_ = sinf(0.5f*wp[l*3+2]);
                #pragma unroll
                for (int b=0;b<8;b+=2){ float xx=v[b], yy=v[b+1]; v[b]=cc*xx-sc_*yy; v[b+1]=sc_*xx+cc*yy; }
                #pragma unroll
                for (int g=0; g<8; g+=4)
                    #pragma unroll
                    for (int i=0;i<2;i++){ int a=g+i, b=g+i+2; float xx=v[a], yy=v[b]; v[a]=cb*xx-sb*yy; v[b]=sb*xx+cb*yy; }
                #pragma unroll
                for (int i=0;i<4;i++){ float xx=v[i], yy=v[i+4]; v[i]=ca*xx-sa*yy; v[i+4]=sa*xx+ca*yy; }
                // CNOT ring: new[perm[r]] = old[r]; perm = {0,5,7,2,3,6,4,1}
                float nv[8];
                nv[0]=v[0]; nv[5]=v[1]; nv[7]=v[2]; nv[2]=v[3];
                nv[3]=v[4]; nv[6]=v[5]; nv[4]=v[6]; nv[1]=v[7];
                #pragma unroll
                for (int r=0;r<8;r++) v[r]=nv[r];
            }
            #pragma unroll
            for (int r=0;r<4;r++) llc_store(Vg + ch*16 + r*4 + k, v[r]);  // U[r][k]
        }
    }
    gbar(ctr, 0);

    // P1: L1  z -> sX; stats -> g2 (64 ch, N=65536)
    qcnn_phase<256,4,4,false,true,false>(z, Vg, nullptr, nullptr, nullptr, nullptr,
        0.0f, nullptr, ws+OFF_G2S, ws+OFF_G2Q, sBin, sV, sRed, sX);
    gbar(ctr, 1);

    // P2: L2  relu(bn(sX)) -> sX; stats -> g3 (16 ch, N=262144)
    qcnn_phase<64,8,8,true,false,false>(nullptr, Vg+256*16, ws+OFF_G2S, ws+OFF_G2Q,
        gamma2, beta2, 1.0f/65536.0f, nullptr, ws+OFF_G3S, ws+OFF_G3Q, sBin, sV, sRed, sX);
    gbar(ctr, 2);

    // P3: L3 -> sX; stats -> g4 (4 ch, N=1048576)
    qcnn_phase<16,16,16,true,false,false>(nullptr, Vg+320*16, ws+OFF_G3S, ws+OFF_G3Q,
        gamma3, beta3, 1.0f/262144.0f, nullptr, ws+OFF_G4S, ws+OFF_G4Q, sBin, sV, sRed, sX);
    gbar(ctr, 3);

    // P4: L4 -> sX AND s4 (out slot 1); stats -> gf (1 ch, N=4194304)
    qcnn_phase<4,32,32,true,false,true>(nullptr, Vg+336*16, ws+OFF_G4S, ws+OFF_G4Q,
        gamma4, beta4, 1.0f/1048576.0f, s4, ws+OFF_GFS, ws+OFF_GFQ, sBin, sV, sRed, sX);
    gbar(ctr, 4);

    // P5: final  s4_bn -> out slot 2, tanh -> out slot 0 (reads OWN sX slots)
    {
        float v = 0.0f;
        if (threadIdx.x < 64)
            v = llc_load(ws + (threadIdx.x < 32 ? OFF_GFS + threadIdx.x
                                                : OFF_GFQ + threadIdx.x - 32));
        #pragma unroll
        for (int off=1; off<32; off<<=1) v += __shfl_xor(v, off);
        if (threadIdx.x == 0)  sRed[0] = v;   // sum
        if (threadIdx.x == 32) sRed[1] = v;   // sum of squares
        __syncthreads();
        float s = sRed[0], q = sRed[1];
        float mean = s * (1.0f/4194304.0f);
        float var  = q * (1.0f/4194304.0f) - mean*mean;
        float rinv = 1.0f / sqrtf(var + 1e-5f);
        float sc = gammaf[0]*rinv;
        float sh = betaf[0] - mean*sc;
        #pragma unroll
        for (int it=0; it<2; ++it){
            const int b = (it<<9) + (int)(blockIdx.x>>1);
            const size_t go = ((size_t)b<<12) + (w<<11) + 4*threadIdx.x;
            float4 vv = *reinterpret_cast<const float4*>(&sX[it*2048 + 4*threadIdx.x]);
            float4 bn = make_float4(vv.x*sc+sh, vv.y*sc+sh, vv.z*sc+sh, vv.w*sc+sh);
            *reinterpret_cast<float4*>(s4bn + go) = bn;
            *reinterpret_cast<float4*>(out + go) =
                make_float4(tanhf(bn.x), tanhf(bn.y), tanhf(bn.z), tanhf(bn.w));
        }
    }
}

extern "C" void kernel_launch(void* const* d_in, const int* in_sizes, int n_in,
                              void* d_out, int out_size, void* d_ws, size_t ws_size,
                              hipStream_t stream)
{
    const float* z      = (const float*)d_in[0];
    const float* w1     = (const float*)d_in[1];
    const float* w2     = (const float*)d_in[2];
    const float* w3     = (const float*)d_in[3];
    const float* w4     = (const float*)d_in[4];
    const float* gamma2 = (const float*)d_in[5];
    const float* beta2  = (const float*)d_in[6];
    const float* gamma3 = (const float*)d_in[7];
    const float* beta3  = (const float*)d_in[8];
    const float* gamma4 = (const float*)d_in[9];
    const float* beta4  = (const float*)d_in[10];
    const float* gammaf = (const float*)d_in[11];
    const float* betaf  = (const float*)d_in[12];
    float* out = (float*)d_out;
    float* ws  = (float*)d_ws;

    // zero BN partial slots + barrier counters/flags (V table fully overwritten)
    hipMemsetAsync(ws, 0, (5504 + 5*PHASE_STRIDE) * sizeof(float), stream);

    fused_all<<<NBLK, TPB, 0, stream>>>(
        z, w1, w2, w3, w4, gamma2, beta2, gamma3, beta3,
        gamma4, beta4, gammaf, betaf, out, ws);
}